// Round 11
// baseline (201.032 us; speedup 1.0000x reference)
//
#include <hip/hip_runtime.h>

// LTFGW semi-relaxed FGW — round 25: KPB=1/BS=128 (isolated geometry step).
// r24 post-mortem: WIN (total 187.5 -> 179.0; pre ~6us after LDS diet).
//   Ledger: srfgw 119.6 + pre ~6 + harness ~54.
// r25: small-barrier-domain mechanism (confirmed r19/r22/r23) one step further:
//   KPB=1, BS=128 -> LDS ~7.9KB, 16 blocks/CU (thread-capped), 2-wave barrier
//   domains. Both past failure modes structurally removed: setup hoisted (r20),
//   VGPR ceiling 64 at launch_bounds(128,8) >> 36 used (r22/r23 lesson).
//   Marginal duplicated setup per extra kb sweep: nbr+mask+C2sq coalesced
//   loads only (~1us total).
//   s_adj overlay no longer fits (7616 > s_T 5712): useM=0 fallback now builds
//   masks reading dst direct from global (correct-only path, never exercised).
// pre_kernel byte-identical r24. srfgw inner math byte-identical r13 lineage.
// Predict: srfgw 119.6 -> 110-116, VALUBusy 85-90, VGPR 36 (no spill),
//   total -> ~170-175. Falsifier: srfgw >=119 @ VGPR36 -> VALU floor, ROOFLINE.

#define NN    6000
#define DEG   16
#define MM    17
#define NTPL  16
#define MT    10
#define NF    128
#define NITER 10
#define KPB   1
#define NPB   7
#define BS    128
#define RS    12            // padded T row stride (floats)
#define LOG2E 1.44269504088896340736f

__device__ __forceinline__ float fexp2(float x) { return __builtin_amdgcn_exp2f(x); }
__device__ __forceinline__ float frcp(float x)  { return __builtin_amdgcn_rcpf(x); }

// ---------------- fused precompute: gcost (no-xs) blocks + mask blocks (r24 verbatim)
#define GBN  64             // nodes per gcost block
#define GBK  32             // kts per gcost block
#define GPAD 132            // LDS row stride in floats (fs)
#define GNT  ((NN + GBN - 1) / GBN)             // 94
#define GKT  ((NTPL * MT) / GBK)                // 5
#define GBLK (GNT * GKT)                        // 470
#define FMNPB 4             // nodes per mask block (128 thr)
#define MBLK ((NN + FMNPB - 1) / FMNPB)         // 1500

__global__ __launch_bounds__(128) void pre_kernel(
    const float* __restrict__ x, const float* __restrict__ F2g,
    const float* __restrict__ alpha0, const int* __restrict__ dst,
    float* __restrict__ G, unsigned* __restrict__ maskg)
{
    __shared__ __align__(16) char smem[17920];   // fs 16896 + ps 512 (mask: 4896)
    const int bx  = blockIdx.x;
    const int tid = threadIdx.x;

    if (bx < GBLK) {
        // ---- gcost: F2 tile in LDS, x straight from global (L2-hot) ----
        float (*fs)[GPAD] = reinterpret_cast<float(*)[GPAD]>(smem);          // [32][132]
        float (*ps)[4]    = reinterpret_cast<float(*)[4]>(smem + 16896);     // [32][4]

        const int n0 = (bx % GNT) * GBN;
        const int k0 = (bx / GNT) * GBK;

        for (int i = tid; i < GBK * 32; i += 128) {
            int r = i >> 5, c = i & 31;
            float4 w = reinterpret_cast<const float4*>(F2g + (size_t)(k0 + r) * NF)[c];
            *reinterpret_cast<float4*>(&fs[r][c * 4]) = w;
        }
        __syncthreads();

        {
            int r = tid & 31, q = tid >> 5;
            const float4* fp = reinterpret_cast<const float4*>(&fs[r][q * 32]);
            float s = 0.f;
            #pragma unroll
            for (int c = 0; c < 8; c++) {
                float4 w = fp[c];
                s += w.x * w.x + w.y * w.y + w.z * w.z + w.w * w.w;
            }
            ps[r][q] = s;
        }
        __syncthreads();

        const int jk = tid & 7;
        const int nn = tid >> 3;

        const float4* xr[4];
        #pragma unroll
        for (int c = 0; c < 4; c++) {
            int v = n0 + nn + 16 * c; if (v >= NN) v = NN - 1;
            xr[c] = reinterpret_cast<const float4*>(x + (size_t)v * NF);
        }

        float acc[4][4];
        #pragma unroll
        for (int c = 0; c < 4; c++)
            #pragma unroll
            for (int t = 0; t < 4; t++) acc[c][t] = 0.f;

        #pragma unroll 4
        for (int f = 0; f < NF / 4; f++) {
            float4 xa[4], fb[4];
            #pragma unroll
            for (int c = 0; c < 4; c++)
                xa[c] = xr[c][f];
            #pragma unroll
            for (int t = 0; t < 4; t++)
                fb[t] = *reinterpret_cast<const float4*>(&fs[jk + 8 * t][f * 4]);
            #pragma unroll
            for (int c = 0; c < 4; c++)
                #pragma unroll
                for (int t = 0; t < 4; t++) {
                    acc[c][t] = fmaf(xa[c].x, fb[t].x, acc[c][t]);
                    acc[c][t] = fmaf(xa[c].y, fb[t].y, acc[c][t]);
                    acc[c][t] = fmaf(xa[c].z, fb[t].z, acc[c][t]);
                    acc[c][t] = fmaf(xa[c].w, fb[t].w, acc[c][t]);
                }
        }

        const float alpha  = 1.f / (1.f + __expf(-alpha0[0]));
        const float mcoefl = (1.f - alpha) * 10.f * LOG2E;
        const float m2     = -2.f * mcoefl;

        #pragma unroll
        for (int t = 0; t < 4; t++) {
            int krow = jk + 8 * t;
            float sq   = ps[krow][0] + ps[krow][1] + ps[krow][2] + ps[krow][3];
            float base = mcoefl * sq;
            int   kt   = k0 + krow;
            #pragma unroll
            for (int c = 0; c < 4; c++) {
                int v = n0 + nn + 16 * c;
                if (v < NN)
                    G[(size_t)v * (NTPL * MT) + kt] = fmaf(m2, acc[c][t], base);
            }
        }
    } else {
        // ---- mask build (FMNPB=4, 128 threads; same dual-atomicOr semantics) ----
        int      (*m_nbr)[MM]  = reinterpret_cast<int(*)[MM]>(smem);                 // 272 B
        int      (*m_adj)[DEG] = reinterpret_cast<int(*)[DEG]>(smem + 272);          // 4352 B
        unsigned (*m_msk)[MM]  = reinterpret_cast<unsigned(*)[MM]>(smem + 272 + 4352);

        const int n0 = (bx - GBLK) * FMNPB;

        if (tid < FMNPB * MM) {                          // 68 <= 128
            int node = tid / MM, a0 = tid - node * MM;
            int nd  = n0 + node;
            int ndc = nd < NN ? nd : NN - 1;
            m_nbr[node][a0] = (a0 == 0) ? ndc : dst[(size_t)ndc * DEG + a0 - 1];
            m_msk[node][a0] = 0u;
        }
        __syncthreads();

        for (int i = tid; i < FMNPB * MM * DEG; i += 128) {   // 1088
            int r = i >> 4, j = i & 15;
            int node = r / MM, a0 = r - node * MM;
            m_adj[r][j] = dst[(size_t)m_nbr[node][a0] * DEG + j];
        }
        __syncthreads();

        for (int i = tid; i < FMNPB * MM * MM; i += 128) {    // 1156
            int node = i / (MM * MM), rr = i - node * (MM * MM);
            int pa = rr / MM, pb = rr - pa * MM;
            int vtgt = m_nbr[node][pb];
            const int* ar = m_adj[node * MM + pa];
            bool e = false;
            #pragma unroll
            for (int j = 0; j < DEG; j++) e = e | (ar[j] == vtgt);
            if (e) {
                atomicOr(&m_msk[node][pa], 1u << pb);
                atomicOr(&m_msk[node][pb], 1u << pa);
            }
        }
        __syncthreads();

        if (tid < FMNPB * MM) {
            int node = tid / MM, a0 = tid - node * MM;
            int nd = n0 + node;
            if (nd < NN)
                maskg[(size_t)nd * MM + a0] = m_msk[node][a0];
        }
    }
}

// ---------------- main kernel (r13-lineage math; KPB=1/BS=128; no s_adj)
__global__ __launch_bounds__(BS, 8) void srfgw_kernel(
    const float* __restrict__ x,
    const int*   __restrict__ dst,
    const float* __restrict__ C2g,
    const float* __restrict__ F2g,
    const float* __restrict__ alpha0,
    const float* __restrict__ G,
    const unsigned* __restrict__ maskg,
    int useG, int useM,
    float*       __restrict__ out)
{
    const int nb  = blockIdx.x * NPB;
    const int kb  = blockIdx.y * KPB;
    const int tid = threadIdx.x;

    __shared__ __align__(16) float s_T[KPB][NPB][MM][RS];     // 5712 B
    __shared__ __align__(16) float s_C2sq[KPB][MT][RS];       // 480 B
    __shared__ __align__(16) float s_q[KPB][NPB][RS];         // 336 B
    __shared__ __align__(16) float s_cc[KPB][NPB][RS];        // 336 B
    __shared__ __align__(16) float s_A[KPB][RS];              // 48 B
    __shared__ __align__(16) float s_B[KPB][RS];              // 48 B
    __shared__ int      s_nbr[NPB][MM];                       // 476 B
    __shared__ unsigned s_mask[NPB][MM];                      // 476 B

    const float aval  = alpha0[0];
    const float alpha = 1.f / (1.f + __expf(-aval));
    const float gcoef = 2.f * alpha * 10.f;
    const float tgl   = 2.f * gcoef * LOG2E;
    const float gl2   = gcoef * LOG2E;

    // phase 1: nbr + mask (load precomputed when useM)
    if (tid < NPB * MM) {
        int node = tid / MM, a0 = tid - node * MM;
        int nd  = nb + node;
        int ndc = nd < NN ? nd : NN - 1;
        s_nbr[node][a0]  = (a0 == 0) ? ndc : dst[(size_t)ndc * DEG + a0 - 1];
        s_mask[node][a0] = useM ? maskg[(size_t)ndc * MM + a0] : 0u;
    }
    __syncthreads();

    // phase 2: C2sq; iter-0 fold constants
    for (int i = tid; i < KPB * MT * MT; i += BS) {
        int kk = i / (MT * MT), rr = i - kk * (MT * MT);
        int rs = rr / MT, rt = rr - rs * MT;
        float v = C2g[(size_t)kb * MT * MT + i];
        s_C2sq[kk][rs][rt] = gl2 * v * v;
    }
    if (tid < KPB * MT) {
        int kk = tid / MT, s = tid - kk * MT;
        const float* cr = C2g + (size_t)(kb + kk) * MT * MT + s * MT;
        float rs = 0.f, rq = 0.f;
        #pragma unroll
        for (int t = 0; t < MT; t++) { float c = cr[t]; rs += c; rq = fmaf(c, c, rq); }
        s_A[kk][s] = (tgl / 170.f) * rs;
        s_B[kk][s] = 0.1f * gl2 * rq;
    }
    __syncthreads();

    // phase 3: (fallback only; never taken when workspace suffices)
    // builds masks reading dst straight from global — correct, slow.
    if (!useM) {
        for (int i = tid; i < NPB * MM * MM; i += BS) {
            int node = i / (MM * MM), rr = i - node * (MM * MM);
            int pa = rr / MM, pb = rr - pa * MM;
            int vtgt = s_nbr[node][pb];
            const int* ar = dst + (size_t)s_nbr[node][pa] * DEG;
            bool e = false;
            #pragma unroll
            for (int j = 0; j < DEG; j++) e = e | (ar[j] == vtgt);
            if (e) {
                atomicOr(&s_mask[node][pa], 1u << pb);
                atomicOr(&s_mask[node][pb], 1u << pa);
            }
        }
        __syncthreads();
    }

    // ---- row mapping: kh wave-uniform (0 at BS=128); 119 rows in 128 lanes ----
    const int  kh     = tid >> 7;              // 0
    const int  L      = tid & 127;
    const bool rvalid = L < NPB * MM;          // 119
    int gR = L / MM;
    int aR = L - gR * MM;
    if (!rvalid) { gR = 0; aR = 0; }

    const int k_u = __builtin_amdgcn_readfirstlane(kb + kh);
    const float* __restrict__ c2p = C2g + (size_t)k_u * MT * MT;

    const int vv = s_nbr[gR][aR];

    float Mc[MT];
    if (useG) {
        const float2* gp = reinterpret_cast<const float2*>(G + (size_t)vv * (NTPL * MT) + k_u * MT);
        #pragma unroll
        for (int j = 0; j < 5; j++) {
            float2 w = gp[j];
            Mc[2 * j] = w.x; Mc[2 * j + 1] = w.y;
        }
    } else {
        float dot[MT], sq2[MT];
        #pragma unroll
        for (int t = 0; t < MT; t++) { dot[t] = 0.f; sq2[t] = 0.f; }
        const float4* xr = reinterpret_cast<const float4*>(x + (size_t)vv * NF);
        const float4* fr = reinterpret_cast<const float4*>(F2g + (size_t)k_u * MT * NF);
        for (int f = 0; f < NF / 4; f++) {
            float4 xa = xr[f];
            #pragma unroll
            for (int t = 0; t < MT; t++) {
                float4 b = fr[t * (NF / 4) + f];
                dot[t] += xa.x * b.x + xa.y * b.y + xa.z * b.z + xa.w * b.w;
                sq2[t] += b.x * b.x + b.y * b.y + b.z * b.z + b.w * b.w;
            }
        }
        const float mcoefl = (1.f - alpha) * 10.f * LOG2E;
        #pragma unroll
        for (int t = 0; t < MT; t++) Mc[t] = mcoefl * (sq2[t] - 2.f * dot[t]);
    }

    unsigned mask = rvalid ? s_mask[gR][aR] : 0u;
    const int  pcnt = __popc(mask);
    const bool cmpl = pcnt > 8;
    unsigned   lmask = cmpl ? (~mask & 0x1FFFFu) : mask;
    if (!rvalid) lmask = 0u;
    const float sgn = cmpl ? -1.f : 1.f;
    const float P   = 1.f / 17.f;

    // ---- iter-0 analytic fold ----
    float lt[MT];
    {
        const float pcf = (float)pcnt;
        const float2* Ap = reinterpret_cast<const float2*>(&s_A[kh][0]);
        const float2* Bp = reinterpret_cast<const float2*>(&s_B[kh][0]);
        #pragma unroll
        for (int j = 0; j < 5; j++) {
            float2 av = Ap[j], bv = Bp[j];
            lt[2 * j]     = fmaf(pcf, av.x, -bv.x - Mc[2 * j]);
            lt[2 * j + 1] = fmaf(pcf, av.y, -bv.y - Mc[2 * j + 1]);
        }
    }

    // ---- colsum/cc mapping: tid < 70 -> (ck, cn, ct) ----
    const bool cvalid = tid < KPB * NPB * MT;  // 70
    int ck = 0, cn = 0, ct = 0;
    if (cvalid) {
        ck = tid / (NPB * MT);
        int rem = tid - ck * (NPB * MT);
        cn = rem / MT;
        ct = rem - cn * MT;
    }
    float qa = 0.f;

    float4* Trow = reinterpret_cast<float4*>(&s_T[kh][gR][aR][0]);

    for (int it = 1; it <= NITER; it++) {
        // thread-local softmax (log2 domain)
        float mx = lt[0];
        #pragma unroll
        for (int t = 1; t < MT; t++) mx = fmaxf(mx, lt[t]);
        float e[MT], ss = 0.f;
        #pragma unroll
        for (int t = 0; t < MT; t++) { e[t] = fexp2(lt[t] - mx); ss += e[t]; }
        float sc = P * frcp(ss);
        #pragma unroll
        for (int t = 0; t < MT; t++) e[t] *= sc;

        if (rvalid) {
            Trow[0] = make_float4(e[0], e[1], e[2], e[3]);
            Trow[1] = make_float4(e[4], e[5], e[6], e[7]);
            reinterpret_cast<float2*>(Trow)[4] = make_float2(e[8], e[9]);
        }
        __syncthreads();                         // (1) T visible

        // colsum -> q
        if (cvalid) {
            const float* colp = &s_T[ck][cn][0][ct];
            float s0 = 0.f;
            #pragma unroll
            for (int m = 0; m < MM; m++) s0 += colp[m * RS];
            qa = s0;
            s_q[ck][cn][ct] = s0;
        }
        __syncthreads();                         // (2) q visible
        if (it == NITER) break;

        // cc (cvalid threads)
        if (cvalid) {
            const float4* qp4 = reinterpret_cast<const float4*>(&s_q[ck][cn][0]);
            float4 qx = qp4[0], qy = qp4[1];
            float2 qz = reinterpret_cast<const float2*>(qp4)[4];
            const float4* cr = reinterpret_cast<const float4*>(&s_C2sq[ck][ct][0]);
            float4 ca = cr[0], cb = cr[1];
            float2 c2 = reinterpret_cast<const float2*>(cr)[4];
            float cc = qx.x * ca.x + qx.y * ca.y + qx.z * ca.z + qx.w * ca.w
                     + qy.x * cb.x + qy.y * cb.y + qy.z * cb.z + qy.w * cb.w
                     + qz.x * c2.x + qz.y * c2.y;
            s_cc[ck][cn][ct] = cc;
        }

        // row work: q read, Y1, y2 matvec, partial update (pre-ccr)
        float q[MT];
        {
            const float4* qp4 = reinterpret_cast<const float4*>(&s_q[kh][gR][0]);
            float4 qx = qp4[0], qy = qp4[1];
            float2 qz = reinterpret_cast<const float2*>(qp4)[4];
            q[0] = qx.x; q[1] = qx.y; q[2] = qx.z; q[3] = qx.w;
            q[4] = qy.x; q[5] = qy.y; q[6] = qy.z; q[7] = qy.w;
            q[8] = qz.x; q[9] = qz.y;
        }
        float y1[MT];
        #pragma unroll
        for (int t = 0; t < MT; t++) y1[t] = cmpl ? q[t] : 0.f;
        unsigned mm = lmask;
        while (mm) {
            int b = __ffs(mm) - 1;
            mm &= mm - 1;
            const float4* rb4 = reinterpret_cast<const float4*>(&s_T[kh][gR][b][0]);
            float4 ra = rb4[0], rb = rb4[1];
            float2 rc = reinterpret_cast<const float2*>(rb4)[4];
            y1[0] += sgn * ra.x; y1[1] += sgn * ra.y; y1[2] += sgn * ra.z; y1[3] += sgn * ra.w;
            y1[4] += sgn * rb.x; y1[5] += sgn * rb.y; y1[6] += sgn * rb.z; y1[7] += sgn * rb.w;
            y1[8] += sgn * rc.x; y1[9] += sgn * rc.y;
        }
        #pragma unroll
        for (int s = 0; s < MT; s++) {
            float y2 = 0.f;
            #pragma unroll
            for (int t = 0; t < MT; t++) y2 = fmaf(y1[t], c2p[s * MT + t], y2);
            lt[s] += tgl * y2 - Mc[s];           // ccr applied after barrier
        }
        __syncthreads();                         // (3) cc visible

        {
            const float4* cp = reinterpret_cast<const float4*>(&s_cc[kh][gR][0]);
            float4 ca = cp[0], cb = cp[1];
            float2 c2 = reinterpret_cast<const float2*>(cp)[4];
            lt[0] -= ca.x; lt[1] -= ca.y; lt[2] -= ca.z; lt[3] -= ca.w;
            lt[4] -= cb.x; lt[5] -= cb.y; lt[6] -= cb.z; lt[7] -= cb.w;
            lt[8] -= c2.x; lt[9] -= c2.y;
        }
    }

    if (cvalid) {
        int nOut = nb + cn;
        if (nOut < NN)
            out[(size_t)nOut * (NTPL * MT) + (kb + ck) * MT + ct] = qa;
    }
}

extern "C" void kernel_launch(void* const* d_in, const int* in_sizes, int n_in,
                              void* d_out, int out_size, void* d_ws, size_t ws_size,
                              hipStream_t stream) {
    const float* x      = (const float*)d_in[0];
    const int*   eidx   = (const int*)d_in[1];
    const float* tmpl   = (const float*)d_in[2];
    const float* tmplf  = (const float*)d_in[3];
    const float* alpha0 = (const float*)d_in[4];
    float*       outp   = (float*)d_out;

    const int* dst = eidx + NN * DEG;
    float* G = (float*)d_ws;
    const size_t gbytes = (size_t)NN * NTPL * MT * sizeof(float);       // 3,840,000
    const size_t mbytes = (size_t)NN * MM * sizeof(unsigned);           // 408,000
    int useG = (ws_size >= gbytes) ? 1 : 0;
    int useM = (ws_size >= gbytes + mbytes) ? 1 : 0;
    unsigned* maskg = (unsigned*)((char*)d_ws + gbytes);

    if (useG && useM) {
        pre_kernel<<<dim3(GBLK + MBLK), dim3(128), 0, stream>>>(
            x, tmplf, alpha0, dst, G, maskg);
    } else if (useG) {
        pre_kernel<<<dim3(GBLK), dim3(128), 0, stream>>>(
            x, tmplf, alpha0, dst, G, maskg);
    }

    srfgw_kernel<<<dim3((NN + NPB - 1) / NPB, NTPL / KPB), dim3(BS), 0, stream>>>(
        x, dst, tmpl, tmplf, alpha0, G, maskg, useG, useM, outp);
}

// Round 12
// 178.722 us; speedup vs baseline: 1.1248x; 1.1248x over previous
//
#include <hip/hip_runtime.h>

// LTFGW semi-relaxed FGW — round 26: KPB=1/BS=128 retry, register trap removed.
// r25 post-mortem: CONFOUNDED AGAIN — launch_bounds(*,8) makes hipcc clamp to
//   32 VGPR (observed r22 AND r25; naive pool math says 64 fits 36 — toolchain
//   behavior, not HW). WRITE 4500->6000KB = scratch spills. r25 tested
//   "KPB=1 + spills", not "KPB=1". min-waves=6 (r23) reliably yields 36+VGPR.
// r26: byte-identical to r25 except launch_bounds(128,6). Runtime occupancy is
//   set by ACTUAL alloc (<=64 VGPR -> still 8 waves/SIMD = 16 blocks/CU).
// Strict falsifiers: VGPR>=36 & WRITE ~4500KB required; then srfgw 107-114
//   expected. If clean AND >=119 -> ladder exhausted, revert r24 + ROOFLINE.
// pre_kernel byte-identical r24. srfgw inner math byte-identical r13 lineage.

#define NN    6000
#define DEG   16
#define MM    17
#define NTPL  16
#define MT    10
#define NF    128
#define NITER 10
#define KPB   1
#define NPB   7
#define BS    128
#define RS    12            // padded T row stride (floats)
#define LOG2E 1.44269504088896340736f

__device__ __forceinline__ float fexp2(float x) { return __builtin_amdgcn_exp2f(x); }
__device__ __forceinline__ float frcp(float x)  { return __builtin_amdgcn_rcpf(x); }

// ---------------- fused precompute: gcost (no-xs) blocks + mask blocks (r24 verbatim)
#define GBN  64             // nodes per gcost block
#define GBK  32             // kts per gcost block
#define GPAD 132            // LDS row stride in floats (fs)
#define GNT  ((NN + GBN - 1) / GBN)             // 94
#define GKT  ((NTPL * MT) / GBK)                // 5
#define GBLK (GNT * GKT)                        // 470
#define FMNPB 4             // nodes per mask block (128 thr)
#define MBLK ((NN + FMNPB - 1) / FMNPB)         // 1500

__global__ __launch_bounds__(128) void pre_kernel(
    const float* __restrict__ x, const float* __restrict__ F2g,
    const float* __restrict__ alpha0, const int* __restrict__ dst,
    float* __restrict__ G, unsigned* __restrict__ maskg)
{
    __shared__ __align__(16) char smem[17920];   // fs 16896 + ps 512 (mask: 4896)
    const int bx  = blockIdx.x;
    const int tid = threadIdx.x;

    if (bx < GBLK) {
        // ---- gcost: F2 tile in LDS, x straight from global (L2-hot) ----
        float (*fs)[GPAD] = reinterpret_cast<float(*)[GPAD]>(smem);          // [32][132]
        float (*ps)[4]    = reinterpret_cast<float(*)[4]>(smem + 16896);     // [32][4]

        const int n0 = (bx % GNT) * GBN;
        const int k0 = (bx / GNT) * GBK;

        for (int i = tid; i < GBK * 32; i += 128) {
            int r = i >> 5, c = i & 31;
            float4 w = reinterpret_cast<const float4*>(F2g + (size_t)(k0 + r) * NF)[c];
            *reinterpret_cast<float4*>(&fs[r][c * 4]) = w;
        }
        __syncthreads();

        {
            int r = tid & 31, q = tid >> 5;
            const float4* fp = reinterpret_cast<const float4*>(&fs[r][q * 32]);
            float s = 0.f;
            #pragma unroll
            for (int c = 0; c < 8; c++) {
                float4 w = fp[c];
                s += w.x * w.x + w.y * w.y + w.z * w.z + w.w * w.w;
            }
            ps[r][q] = s;
        }
        __syncthreads();

        const int jk = tid & 7;
        const int nn = tid >> 3;

        const float4* xr[4];
        #pragma unroll
        for (int c = 0; c < 4; c++) {
            int v = n0 + nn + 16 * c; if (v >= NN) v = NN - 1;
            xr[c] = reinterpret_cast<const float4*>(x + (size_t)v * NF);
        }

        float acc[4][4];
        #pragma unroll
        for (int c = 0; c < 4; c++)
            #pragma unroll
            for (int t = 0; t < 4; t++) acc[c][t] = 0.f;

        #pragma unroll 4
        for (int f = 0; f < NF / 4; f++) {
            float4 xa[4], fb[4];
            #pragma unroll
            for (int c = 0; c < 4; c++)
                xa[c] = xr[c][f];
            #pragma unroll
            for (int t = 0; t < 4; t++)
                fb[t] = *reinterpret_cast<const float4*>(&fs[jk + 8 * t][f * 4]);
            #pragma unroll
            for (int c = 0; c < 4; c++)
                #pragma unroll
                for (int t = 0; t < 4; t++) {
                    acc[c][t] = fmaf(xa[c].x, fb[t].x, acc[c][t]);
                    acc[c][t] = fmaf(xa[c].y, fb[t].y, acc[c][t]);
                    acc[c][t] = fmaf(xa[c].z, fb[t].z, acc[c][t]);
                    acc[c][t] = fmaf(xa[c].w, fb[t].w, acc[c][t]);
                }
        }

        const float alpha  = 1.f / (1.f + __expf(-alpha0[0]));
        const float mcoefl = (1.f - alpha) * 10.f * LOG2E;
        const float m2     = -2.f * mcoefl;

        #pragma unroll
        for (int t = 0; t < 4; t++) {
            int krow = jk + 8 * t;
            float sq   = ps[krow][0] + ps[krow][1] + ps[krow][2] + ps[krow][3];
            float base = mcoefl * sq;
            int   kt   = k0 + krow;
            #pragma unroll
            for (int c = 0; c < 4; c++) {
                int v = n0 + nn + 16 * c;
                if (v < NN)
                    G[(size_t)v * (NTPL * MT) + kt] = fmaf(m2, acc[c][t], base);
            }
        }
    } else {
        // ---- mask build (FMNPB=4, 128 threads; same dual-atomicOr semantics) ----
        int      (*m_nbr)[MM]  = reinterpret_cast<int(*)[MM]>(smem);                 // 272 B
        int      (*m_adj)[DEG] = reinterpret_cast<int(*)[DEG]>(smem + 272);          // 4352 B
        unsigned (*m_msk)[MM]  = reinterpret_cast<unsigned(*)[MM]>(smem + 272 + 4352);

        const int n0 = (bx - GBLK) * FMNPB;

        if (tid < FMNPB * MM) {                          // 68 <= 128
            int node = tid / MM, a0 = tid - node * MM;
            int nd  = n0 + node;
            int ndc = nd < NN ? nd : NN - 1;
            m_nbr[node][a0] = (a0 == 0) ? ndc : dst[(size_t)ndc * DEG + a0 - 1];
            m_msk[node][a0] = 0u;
        }
        __syncthreads();

        for (int i = tid; i < FMNPB * MM * DEG; i += 128) {   // 1088
            int r = i >> 4, j = i & 15;
            int node = r / MM, a0 = r - node * MM;
            m_adj[r][j] = dst[(size_t)m_nbr[node][a0] * DEG + j];
        }
        __syncthreads();

        for (int i = tid; i < FMNPB * MM * MM; i += 128) {    // 1156
            int node = i / (MM * MM), rr = i - node * (MM * MM);
            int pa = rr / MM, pb = rr - pa * MM;
            int vtgt = m_nbr[node][pb];
            const int* ar = m_adj[node * MM + pa];
            bool e = false;
            #pragma unroll
            for (int j = 0; j < DEG; j++) e = e | (ar[j] == vtgt);
            if (e) {
                atomicOr(&m_msk[node][pa], 1u << pb);
                atomicOr(&m_msk[node][pb], 1u << pa);
            }
        }
        __syncthreads();

        if (tid < FMNPB * MM) {
            int node = tid / MM, a0 = tid - node * MM;
            int nd = n0 + node;
            if (nd < NN)
                maskg[(size_t)nd * MM + a0] = m_msk[node][a0];
        }
    }
}

// ---------------- main kernel (r13-lineage math; KPB=1/BS=128; min-waves=6)
__global__ __launch_bounds__(BS, 6) void srfgw_kernel(
    const float* __restrict__ x,
    const int*   __restrict__ dst,
    const float* __restrict__ C2g,
    const float* __restrict__ F2g,
    const float* __restrict__ alpha0,
    const float* __restrict__ G,
    const unsigned* __restrict__ maskg,
    int useG, int useM,
    float*       __restrict__ out)
{
    const int nb  = blockIdx.x * NPB;
    const int kb  = blockIdx.y * KPB;
    const int tid = threadIdx.x;

    __shared__ __align__(16) float s_T[KPB][NPB][MM][RS];     // 5712 B
    __shared__ __align__(16) float s_C2sq[KPB][MT][RS];       // 480 B
    __shared__ __align__(16) float s_q[KPB][NPB][RS];         // 336 B
    __shared__ __align__(16) float s_cc[KPB][NPB][RS];        // 336 B
    __shared__ __align__(16) float s_A[KPB][RS];              // 48 B
    __shared__ __align__(16) float s_B[KPB][RS];              // 48 B
    __shared__ int      s_nbr[NPB][MM];                       // 476 B
    __shared__ unsigned s_mask[NPB][MM];                      // 476 B

    const float aval  = alpha0[0];
    const float alpha = 1.f / (1.f + __expf(-aval));
    const float gcoef = 2.f * alpha * 10.f;
    const float tgl   = 2.f * gcoef * LOG2E;
    const float gl2   = gcoef * LOG2E;

    // phase 1: nbr + mask (load precomputed when useM)
    if (tid < NPB * MM) {
        int node = tid / MM, a0 = tid - node * MM;
        int nd  = nb + node;
        int ndc = nd < NN ? nd : NN - 1;
        s_nbr[node][a0]  = (a0 == 0) ? ndc : dst[(size_t)ndc * DEG + a0 - 1];
        s_mask[node][a0] = useM ? maskg[(size_t)ndc * MM + a0] : 0u;
    }
    __syncthreads();

    // phase 2: C2sq; iter-0 fold constants
    for (int i = tid; i < KPB * MT * MT; i += BS) {
        int kk = i / (MT * MT), rr = i - kk * (MT * MT);
        int rs = rr / MT, rt = rr - rs * MT;
        float v = C2g[(size_t)kb * MT * MT + i];
        s_C2sq[kk][rs][rt] = gl2 * v * v;
    }
    if (tid < KPB * MT) {
        int kk = tid / MT, s = tid - kk * MT;
        const float* cr = C2g + (size_t)(kb + kk) * MT * MT + s * MT;
        float rs = 0.f, rq = 0.f;
        #pragma unroll
        for (int t = 0; t < MT; t++) { float c = cr[t]; rs += c; rq = fmaf(c, c, rq); }
        s_A[kk][s] = (tgl / 170.f) * rs;
        s_B[kk][s] = 0.1f * gl2 * rq;
    }
    __syncthreads();

    // phase 3: (fallback only; never taken when workspace suffices)
    if (!useM) {
        for (int i = tid; i < NPB * MM * MM; i += BS) {
            int node = i / (MM * MM), rr = i - node * (MM * MM);
            int pa = rr / MM, pb = rr - pa * MM;
            int vtgt = s_nbr[node][pb];
            const int* ar = dst + (size_t)s_nbr[node][pa] * DEG;
            bool e = false;
            #pragma unroll
            for (int j = 0; j < DEG; j++) e = e | (ar[j] == vtgt);
            if (e) {
                atomicOr(&s_mask[node][pa], 1u << pb);
                atomicOr(&s_mask[node][pb], 1u << pa);
            }
        }
        __syncthreads();
    }

    // ---- row mapping: kh wave-uniform (0 at BS=128); 119 rows in 128 lanes ----
    const int  kh     = tid >> 7;              // 0
    const int  L      = tid & 127;
    const bool rvalid = L < NPB * MM;          // 119
    int gR = L / MM;
    int aR = L - gR * MM;
    if (!rvalid) { gR = 0; aR = 0; }

    const int k_u = __builtin_amdgcn_readfirstlane(kb + kh);
    const float* __restrict__ c2p = C2g + (size_t)k_u * MT * MT;

    const int vv = s_nbr[gR][aR];

    float Mc[MT];
    if (useG) {
        const float2* gp = reinterpret_cast<const float2*>(G + (size_t)vv * (NTPL * MT) + k_u * MT);
        #pragma unroll
        for (int j = 0; j < 5; j++) {
            float2 w = gp[j];
            Mc[2 * j] = w.x; Mc[2 * j + 1] = w.y;
        }
    } else {
        float dot[MT], sq2[MT];
        #pragma unroll
        for (int t = 0; t < MT; t++) { dot[t] = 0.f; sq2[t] = 0.f; }
        const float4* xr = reinterpret_cast<const float4*>(x + (size_t)vv * NF);
        const float4* fr = reinterpret_cast<const float4*>(F2g + (size_t)k_u * MT * NF);
        for (int f = 0; f < NF / 4; f++) {
            float4 xa = xr[f];
            #pragma unroll
            for (int t = 0; t < MT; t++) {
                float4 b = fr[t * (NF / 4) + f];
                dot[t] += xa.x * b.x + xa.y * b.y + xa.z * b.z + xa.w * b.w;
                sq2[t] += b.x * b.x + b.y * b.y + b.z * b.z + b.w * b.w;
            }
        }
        const float mcoefl = (1.f - alpha) * 10.f * LOG2E;
        #pragma unroll
        for (int t = 0; t < MT; t++) Mc[t] = mcoefl * (sq2[t] - 2.f * dot[t]);
    }

    unsigned mask = rvalid ? s_mask[gR][aR] : 0u;
    const int  pcnt = __popc(mask);
    const bool cmpl = pcnt > 8;
    unsigned   lmask = cmpl ? (~mask & 0x1FFFFu) : mask;
    if (!rvalid) lmask = 0u;
    const float sgn = cmpl ? -1.f : 1.f;
    const float P   = 1.f / 17.f;

    // ---- iter-0 analytic fold ----
    float lt[MT];
    {
        const float pcf = (float)pcnt;
        const float2* Ap = reinterpret_cast<const float2*>(&s_A[kh][0]);
        const float2* Bp = reinterpret_cast<const float2*>(&s_B[kh][0]);
        #pragma unroll
        for (int j = 0; j < 5; j++) {
            float2 av = Ap[j], bv = Bp[j];
            lt[2 * j]     = fmaf(pcf, av.x, -bv.x - Mc[2 * j]);
            lt[2 * j + 1] = fmaf(pcf, av.y, -bv.y - Mc[2 * j + 1]);
        }
    }

    // ---- colsum/cc mapping: tid < 70 -> (ck, cn, ct) ----
    const bool cvalid = tid < KPB * NPB * MT;  // 70
    int ck = 0, cn = 0, ct = 0;
    if (cvalid) {
        ck = tid / (NPB * MT);
        int rem = tid - ck * (NPB * MT);
        cn = rem / MT;
        ct = rem - cn * MT;
    }
    float qa = 0.f;

    float4* Trow = reinterpret_cast<float4*>(&s_T[kh][gR][aR][0]);

    for (int it = 1; it <= NITER; it++) {
        // thread-local softmax (log2 domain)
        float mx = lt[0];
        #pragma unroll
        for (int t = 1; t < MT; t++) mx = fmaxf(mx, lt[t]);
        float e[MT], ss = 0.f;
        #pragma unroll
        for (int t = 0; t < MT; t++) { e[t] = fexp2(lt[t] - mx); ss += e[t]; }
        float sc = P * frcp(ss);
        #pragma unroll
        for (int t = 0; t < MT; t++) e[t] *= sc;

        if (rvalid) {
            Trow[0] = make_float4(e[0], e[1], e[2], e[3]);
            Trow[1] = make_float4(e[4], e[5], e[6], e[7]);
            reinterpret_cast<float2*>(Trow)[4] = make_float2(e[8], e[9]);
        }
        __syncthreads();                         // (1) T visible

        // colsum -> q
        if (cvalid) {
            const float* colp = &s_T[ck][cn][0][ct];
            float s0 = 0.f;
            #pragma unroll
            for (int m = 0; m < MM; m++) s0 += colp[m * RS];
            qa = s0;
            s_q[ck][cn][ct] = s0;
        }
        __syncthreads();                         // (2) q visible
        if (it == NITER) break;

        // cc (cvalid threads)
        if (cvalid) {
            const float4* qp4 = reinterpret_cast<const float4*>(&s_q[ck][cn][0]);
            float4 qx = qp4[0], qy = qp4[1];
            float2 qz = reinterpret_cast<const float2*>(qp4)[4];
            const float4* cr = reinterpret_cast<const float4*>(&s_C2sq[ck][ct][0]);
            float4 ca = cr[0], cb = cr[1];
            float2 c2 = reinterpret_cast<const float2*>(cr)[4];
            float cc = qx.x * ca.x + qx.y * ca.y + qx.z * ca.z + qx.w * ca.w
                     + qy.x * cb.x + qy.y * cb.y + qy.z * cb.z + qy.w * cb.w
                     + qz.x * c2.x + qz.y * c2.y;
            s_cc[ck][cn][ct] = cc;
        }

        // row work: q read, Y1, y2 matvec, partial update (pre-ccr)
        float q[MT];
        {
            const float4* qp4 = reinterpret_cast<const float4*>(&s_q[kh][gR][0]);
            float4 qx = qp4[0], qy = qp4[1];
            float2 qz = reinterpret_cast<const float2*>(qp4)[4];
            q[0] = qx.x; q[1] = qx.y; q[2] = qx.z; q[3] = qx.w;
            q[4] = qy.x; q[5] = qy.y; q[6] = qy.z; q[7] = qy.w;
            q[8] = qz.x; q[9] = qz.y;
        }
        float y1[MT];
        #pragma unroll
        for (int t = 0; t < MT; t++) y1[t] = cmpl ? q[t] : 0.f;
        unsigned mm = lmask;
        while (mm) {
            int b = __ffs(mm) - 1;
            mm &= mm - 1;
            const float4* rb4 = reinterpret_cast<const float4*>(&s_T[kh][gR][b][0]);
            float4 ra = rb4[0], rb = rb4[1];
            float2 rc = reinterpret_cast<const float2*>(rb4)[4];
            y1[0] += sgn * ra.x; y1[1] += sgn * ra.y; y1[2] += sgn * ra.z; y1[3] += sgn * ra.w;
            y1[4] += sgn * rb.x; y1[5] += sgn * rb.y; y1[6] += sgn * rb.z; y1[7] += sgn * rb.w;
            y1[8] += sgn * rc.x; y1[9] += sgn * rc.y;
        }
        #pragma unroll
        for (int s = 0; s < MT; s++) {
            float y2 = 0.f;
            #pragma unroll
            for (int t = 0; t < MT; t++) y2 = fmaf(y1[t], c2p[s * MT + t], y2);
            lt[s] += tgl * y2 - Mc[s];           // ccr applied after barrier
        }
        __syncthreads();                         // (3) cc visible

        {
            const float4* cp = reinterpret_cast<const float4*>(&s_cc[kh][gR][0]);
            float4 ca = cp[0], cb = cp[1];
            float2 c2 = reinterpret_cast<const float2*>(cp)[4];
            lt[0] -= ca.x; lt[1] -= ca.y; lt[2] -= ca.z; lt[3] -= ca.w;
            lt[4] -= cb.x; lt[5] -= cb.y; lt[6] -= cb.z; lt[7] -= cb.w;
            lt[8] -= c2.x; lt[9] -= c2.y;
        }
    }

    if (cvalid) {
        int nOut = nb + cn;
        if (nOut < NN)
            out[(size_t)nOut * (NTPL * MT) + (kb + ck) * MT + ct] = qa;
    }
}

extern "C" void kernel_launch(void* const* d_in, const int* in_sizes, int n_in,
                              void* d_out, int out_size, void* d_ws, size_t ws_size,
                              hipStream_t stream) {
    const float* x      = (const float*)d_in[0];
    const int*   eidx   = (const int*)d_in[1];
    const float* tmpl   = (const float*)d_in[2];
    const float* tmplf  = (const float*)d_in[3];
    const float* alpha0 = (const float*)d_in[4];
    float*       outp   = (float*)d_out;

    const int* dst = eidx + NN * DEG;
    float* G = (float*)d_ws;
    const size_t gbytes = (size_t)NN * NTPL * MT * sizeof(float);       // 3,840,000
    const size_t mbytes = (size_t)NN * MM * sizeof(unsigned);           // 408,000
    int useG = (ws_size >= gbytes) ? 1 : 0;
    int useM = (ws_size >= gbytes + mbytes) ? 1 : 0;
    unsigned* maskg = (unsigned*)((char*)d_ws + gbytes);

    if (useG && useM) {
        pre_kernel<<<dim3(GBLK + MBLK), dim3(128), 0, stream>>>(
            x, tmplf, alpha0, dst, G, maskg);
    } else if (useG) {
        pre_kernel<<<dim3(GBLK), dim3(128), 0, stream>>>(
            x, tmplf, alpha0, dst, G, maskg);
    }

    srfgw_kernel<<<dim3((NN + NPB - 1) / NPB, NTPL / KPB), dim3(BS), 0, stream>>>(
        x, dst, tmpl, tmplf, alpha0, G, maskg, useG, useM, outp);
}

// Round 13
// 170.476 us; speedup vs baseline: 1.1792x; 1.0484x over previous
//
#include <hip/hip_runtime.h>

// LTFGW semi-relaxed FGW — round 27: NPB=15/KPB=1/BS=256 — lane packing 93->99.6%.
// r26 post-mortem: tie (178.7 ~ r24's 179.0). srfgw converges to ~119.5us across
//   KPB=4/2/1 geometries; WRITE inflation at small KPB explained as partial-line
//   write amplification (40B chunks @ 640B stride), not spill; VALU busy ~97-100us
//   in all three -> kernel is at its VALU-issue floor + ~20us barrier skew.
// r27: last counted inefficiency — row mapping wastes 9/128 lanes (119 rows).
//   KPB=1 + NPB=15 + BS=256 packs 255 rows in 256 lanes (99.6%); 6000/15=400
//   tiles exactly. Inner math byte-identical; only mapping constants change.
//   BS=256+min-waves=6 is the r23-verified no-clamp compile (VGPR 36).
//   LDS ~16.3KB -> 8 blocks/CU (thread cap), same residency as r23.
// Predict: VGPR 36-40, srfgw 119.6 -> 112-116, total ~172-176. Falsifier:
//   srfgw >=119 @ VGPR>=36 -> floor reached, revert r24, ROOFLINE.
// pre_kernel byte-identical r24.

#define NN    6000
#define DEG   16
#define MM    17
#define NTPL  16
#define MT    10
#define NF    128
#define NITER 10
#define KPB   1
#define NPB   15
#define BS    256
#define RS    12            // padded T row stride (floats)
#define LOG2E 1.44269504088896340736f

__device__ __forceinline__ float fexp2(float x) { return __builtin_amdgcn_exp2f(x); }
__device__ __forceinline__ float frcp(float x)  { return __builtin_amdgcn_rcpf(x); }

// ---------------- fused precompute: gcost (no-xs) blocks + mask blocks (r24 verbatim)
#define GBN  64             // nodes per gcost block
#define GBK  32             // kts per gcost block
#define GPAD 132            // LDS row stride in floats (fs)
#define GNT  ((NN + GBN - 1) / GBN)             // 94
#define GKT  ((NTPL * MT) / GBK)                // 5
#define GBLK (GNT * GKT)                        // 470
#define FMNPB 4             // nodes per mask block (128 thr)
#define MBLK ((NN + FMNPB - 1) / FMNPB)         // 1500

__global__ __launch_bounds__(128) void pre_kernel(
    const float* __restrict__ x, const float* __restrict__ F2g,
    const float* __restrict__ alpha0, const int* __restrict__ dst,
    float* __restrict__ G, unsigned* __restrict__ maskg)
{
    __shared__ __align__(16) char smem[17920];   // fs 16896 + ps 512 (mask: 4896)
    const int bx  = blockIdx.x;
    const int tid = threadIdx.x;

    if (bx < GBLK) {
        // ---- gcost: F2 tile in LDS, x straight from global (L2-hot) ----
        float (*fs)[GPAD] = reinterpret_cast<float(*)[GPAD]>(smem);          // [32][132]
        float (*ps)[4]    = reinterpret_cast<float(*)[4]>(smem + 16896);     // [32][4]

        const int n0 = (bx % GNT) * GBN;
        const int k0 = (bx / GNT) * GBK;

        for (int i = tid; i < GBK * 32; i += 128) {
            int r = i >> 5, c = i & 31;
            float4 w = reinterpret_cast<const float4*>(F2g + (size_t)(k0 + r) * NF)[c];
            *reinterpret_cast<float4*>(&fs[r][c * 4]) = w;
        }
        __syncthreads();

        {
            int r = tid & 31, q = tid >> 5;
            const float4* fp = reinterpret_cast<const float4*>(&fs[r][q * 32]);
            float s = 0.f;
            #pragma unroll
            for (int c = 0; c < 8; c++) {
                float4 w = fp[c];
                s += w.x * w.x + w.y * w.y + w.z * w.z + w.w * w.w;
            }
            ps[r][q] = s;
        }
        __syncthreads();

        const int jk = tid & 7;
        const int nn = tid >> 3;

        const float4* xr[4];
        #pragma unroll
        for (int c = 0; c < 4; c++) {
            int v = n0 + nn + 16 * c; if (v >= NN) v = NN - 1;
            xr[c] = reinterpret_cast<const float4*>(x + (size_t)v * NF);
        }

        float acc[4][4];
        #pragma unroll
        for (int c = 0; c < 4; c++)
            #pragma unroll
            for (int t = 0; t < 4; t++) acc[c][t] = 0.f;

        #pragma unroll 4
        for (int f = 0; f < NF / 4; f++) {
            float4 xa[4], fb[4];
            #pragma unroll
            for (int c = 0; c < 4; c++)
                xa[c] = xr[c][f];
            #pragma unroll
            for (int t = 0; t < 4; t++)
                fb[t] = *reinterpret_cast<const float4*>(&fs[jk + 8 * t][f * 4]);
            #pragma unroll
            for (int c = 0; c < 4; c++)
                #pragma unroll
                for (int t = 0; t < 4; t++) {
                    acc[c][t] = fmaf(xa[c].x, fb[t].x, acc[c][t]);
                    acc[c][t] = fmaf(xa[c].y, fb[t].y, acc[c][t]);
                    acc[c][t] = fmaf(xa[c].z, fb[t].z, acc[c][t]);
                    acc[c][t] = fmaf(xa[c].w, fb[t].w, acc[c][t]);
                }
        }

        const float alpha  = 1.f / (1.f + __expf(-alpha0[0]));
        const float mcoefl = (1.f - alpha) * 10.f * LOG2E;
        const float m2     = -2.f * mcoefl;

        #pragma unroll
        for (int t = 0; t < 4; t++) {
            int krow = jk + 8 * t;
            float sq   = ps[krow][0] + ps[krow][1] + ps[krow][2] + ps[krow][3];
            float base = mcoefl * sq;
            int   kt   = k0 + krow;
            #pragma unroll
            for (int c = 0; c < 4; c++) {
                int v = n0 + nn + 16 * c;
                if (v < NN)
                    G[(size_t)v * (NTPL * MT) + kt] = fmaf(m2, acc[c][t], base);
            }
        }
    } else {
        // ---- mask build (FMNPB=4, 128 threads; same dual-atomicOr semantics) ----
        int      (*m_nbr)[MM]  = reinterpret_cast<int(*)[MM]>(smem);                 // 272 B
        int      (*m_adj)[DEG] = reinterpret_cast<int(*)[DEG]>(smem + 272);          // 4352 B
        unsigned (*m_msk)[MM]  = reinterpret_cast<unsigned(*)[MM]>(smem + 272 + 4352);

        const int n0 = (bx - GBLK) * FMNPB;

        if (tid < FMNPB * MM) {                          // 68 <= 128
            int node = tid / MM, a0 = tid - node * MM;
            int nd  = n0 + node;
            int ndc = nd < NN ? nd : NN - 1;
            m_nbr[node][a0] = (a0 == 0) ? ndc : dst[(size_t)ndc * DEG + a0 - 1];
            m_msk[node][a0] = 0u;
        }
        __syncthreads();

        for (int i = tid; i < FMNPB * MM * DEG; i += 128) {   // 1088
            int r = i >> 4, j = i & 15;
            int node = r / MM, a0 = r - node * MM;
            m_adj[r][j] = dst[(size_t)m_nbr[node][a0] * DEG + j];
        }
        __syncthreads();

        for (int i = tid; i < FMNPB * MM * MM; i += 128) {    // 1156
            int node = i / (MM * MM), rr = i - node * (MM * MM);
            int pa = rr / MM, pb = rr - pa * MM;
            int vtgt = m_nbr[node][pb];
            const int* ar = m_adj[node * MM + pa];
            bool e = false;
            #pragma unroll
            for (int j = 0; j < DEG; j++) e = e | (ar[j] == vtgt);
            if (e) {
                atomicOr(&m_msk[node][pa], 1u << pb);
                atomicOr(&m_msk[node][pb], 1u << pa);
            }
        }
        __syncthreads();

        if (tid < FMNPB * MM) {
            int node = tid / MM, a0 = tid - node * MM;
            int nd = n0 + node;
            if (nd < NN)
                maskg[(size_t)nd * MM + a0] = m_msk[node][a0];
        }
    }
}

// ---------------- main kernel (r13-lineage math; NPB=15/KPB=1/BS=256)
__global__ __launch_bounds__(BS, 6) void srfgw_kernel(
    const float* __restrict__ x,
    const int*   __restrict__ dst,
    const float* __restrict__ C2g,
    const float* __restrict__ F2g,
    const float* __restrict__ alpha0,
    const float* __restrict__ G,
    const unsigned* __restrict__ maskg,
    int useG, int useM,
    float*       __restrict__ out)
{
    const int nb  = blockIdx.x * NPB;
    const int kb  = blockIdx.y * KPB;   // KPB=1: kb = blockIdx.y
    const int tid = threadIdx.x;

    __shared__ __align__(16) float s_T[NPB][MM][RS];          // 12240 B
    __shared__ __align__(16) float s_C2sq[MT][RS];            // 480 B
    __shared__ __align__(16) float s_q[NPB][RS];              // 720 B
    __shared__ __align__(16) float s_cc[NPB][RS];             // 720 B
    __shared__ __align__(16) float s_A[RS];                   // 48 B
    __shared__ __align__(16) float s_B[RS];                   // 48 B
    __shared__ int      s_nbr[NPB][MM];                       // 1020 B
    __shared__ unsigned s_mask[NPB][MM];                      // 1020 B

    const float aval  = alpha0[0];
    const float alpha = 1.f / (1.f + __expf(-aval));
    const float gcoef = 2.f * alpha * 10.f;
    const float tgl   = 2.f * gcoef * LOG2E;
    const float gl2   = gcoef * LOG2E;

    // phase 1: nbr + mask (load precomputed when useM); 255 <= BS
    if (tid < NPB * MM) {
        int node = tid / MM, a0 = tid - node * MM;
        int nd  = nb + node;
        int ndc = nd < NN ? nd : NN - 1;
        s_nbr[node][a0]  = (a0 == 0) ? ndc : dst[(size_t)ndc * DEG + a0 - 1];
        s_mask[node][a0] = useM ? maskg[(size_t)ndc * MM + a0] : 0u;
    }
    __syncthreads();

    // phase 2: C2sq (100 <= BS); iter-0 fold constants (10 <= BS)
    if (tid < MT * MT) {
        int rs = tid / MT, rt = tid - rs * MT;
        float v = C2g[(size_t)kb * MT * MT + tid];
        s_C2sq[rs][rt] = gl2 * v * v;
    }
    if (tid < MT) {
        const float* cr = C2g + (size_t)kb * MT * MT + tid * MT;
        float rs = 0.f, rq = 0.f;
        #pragma unroll
        for (int t = 0; t < MT; t++) { float c = cr[t]; rs += c; rq = fmaf(c, c, rq); }
        s_A[tid] = (tgl / 170.f) * rs;
        s_B[tid] = 0.1f * gl2 * rq;
    }
    __syncthreads();

    // phase 3: (fallback only; never taken when workspace suffices)
    if (!useM) {
        for (int i = tid; i < NPB * MM * MM; i += BS) {
            int node = i / (MM * MM), rr = i - node * (MM * MM);
            int pa = rr / MM, pb = rr - pa * MM;
            int vtgt = s_nbr[node][pb];
            const int* ar = dst + (size_t)s_nbr[node][pa] * DEG;
            bool e = false;
            #pragma unroll
            for (int j = 0; j < DEG; j++) e = e | (ar[j] == vtgt);
            if (e) {
                atomicOr(&s_mask[node][pa], 1u << pb);
                atomicOr(&s_mask[node][pb], 1u << pa);
            }
        }
        __syncthreads();
    }

    // ---- row mapping: 255 rows flat-packed in 256 lanes (99.6%) ----
    const bool rvalid = tid < NPB * MM;        // 255
    int gR = tid / MM;
    int aR = tid - gR * MM;
    if (!rvalid) { gR = 0; aR = 0; }

    const int k_u = __builtin_amdgcn_readfirstlane(kb);
    const float* __restrict__ c2p = C2g + (size_t)k_u * MT * MT;

    const int vv = s_nbr[gR][aR];

    float Mc[MT];
    if (useG) {
        const float2* gp = reinterpret_cast<const float2*>(G + (size_t)vv * (NTPL * MT) + k_u * MT);
        #pragma unroll
        for (int j = 0; j < 5; j++) {
            float2 w = gp[j];
            Mc[2 * j] = w.x; Mc[2 * j + 1] = w.y;
        }
    } else {
        float dot[MT], sq2[MT];
        #pragma unroll
        for (int t = 0; t < MT; t++) { dot[t] = 0.f; sq2[t] = 0.f; }
        const float4* xr = reinterpret_cast<const float4*>(x + (size_t)vv * NF);
        const float4* fr = reinterpret_cast<const float4*>(F2g + (size_t)k_u * MT * NF);
        for (int f = 0; f < NF / 4; f++) {
            float4 xa = xr[f];
            #pragma unroll
            for (int t = 0; t < MT; t++) {
                float4 b = fr[t * (NF / 4) + f];
                dot[t] += xa.x * b.x + xa.y * b.y + xa.z * b.z + xa.w * b.w;
                sq2[t] += b.x * b.x + b.y * b.y + b.z * b.z + b.w * b.w;
            }
        }
        const float mcoefl = (1.f - alpha) * 10.f * LOG2E;
        #pragma unroll
        for (int t = 0; t < MT; t++) Mc[t] = mcoefl * (sq2[t] - 2.f * dot[t]);
    }

    unsigned mask = rvalid ? s_mask[gR][aR] : 0u;
    const int  pcnt = __popc(mask);
    const bool cmpl = pcnt > 8;
    unsigned   lmask = cmpl ? (~mask & 0x1FFFFu) : mask;
    if (!rvalid) lmask = 0u;
    const float sgn = cmpl ? -1.f : 1.f;
    const float P   = 1.f / 17.f;

    // ---- iter-0 analytic fold ----
    float lt[MT];
    {
        const float pcf = (float)pcnt;
        const float2* Ap = reinterpret_cast<const float2*>(&s_A[0]);
        const float2* Bp = reinterpret_cast<const float2*>(&s_B[0]);
        #pragma unroll
        for (int j = 0; j < 5; j++) {
            float2 av = Ap[j], bv = Bp[j];
            lt[2 * j]     = fmaf(pcf, av.x, -bv.x - Mc[2 * j]);
            lt[2 * j + 1] = fmaf(pcf, av.y, -bv.y - Mc[2 * j + 1]);
        }
    }

    // ---- colsum/cc mapping: tid < 150 -> (cn, ct) ----
    const bool cvalid = tid < NPB * MT;        // 150
    int cn = 0, ct = 0;
    if (cvalid) {
        cn = tid / MT;
        ct = tid - cn * MT;
    }
    float qa = 0.f;

    float4* Trow = reinterpret_cast<float4*>(&s_T[gR][aR][0]);

    for (int it = 1; it <= NITER; it++) {
        // thread-local softmax (log2 domain)
        float mx = lt[0];
        #pragma unroll
        for (int t = 1; t < MT; t++) mx = fmaxf(mx, lt[t]);
        float e[MT], ss = 0.f;
        #pragma unroll
        for (int t = 0; t < MT; t++) { e[t] = fexp2(lt[t] - mx); ss += e[t]; }
        float sc = P * frcp(ss);
        #pragma unroll
        for (int t = 0; t < MT; t++) e[t] *= sc;

        if (rvalid) {
            Trow[0] = make_float4(e[0], e[1], e[2], e[3]);
            Trow[1] = make_float4(e[4], e[5], e[6], e[7]);
            reinterpret_cast<float2*>(Trow)[4] = make_float2(e[8], e[9]);
        }
        __syncthreads();                         // (1) T visible

        // colsum -> q
        if (cvalid) {
            const float* colp = &s_T[cn][0][ct];
            float s0 = 0.f;
            #pragma unroll
            for (int m = 0; m < MM; m++) s0 += colp[m * RS];
            qa = s0;
            s_q[cn][ct] = s0;
        }
        __syncthreads();                         // (2) q visible
        if (it == NITER) break;

        // cc (cvalid threads)
        if (cvalid) {
            const float4* qp4 = reinterpret_cast<const float4*>(&s_q[cn][0]);
            float4 qx = qp4[0], qy = qp4[1];
            float2 qz = reinterpret_cast<const float2*>(qp4)[4];
            const float4* cr = reinterpret_cast<const float4*>(&s_C2sq[ct][0]);
            float4 ca = cr[0], cb = cr[1];
            float2 c2 = reinterpret_cast<const float2*>(cr)[4];
            float cc = qx.x * ca.x + qx.y * ca.y + qx.z * ca.z + qx.w * ca.w
                     + qy.x * cb.x + qy.y * cb.y + qy.z * cb.z + qy.w * cb.w
                     + qz.x * c2.x + qz.y * c2.y;
            s_cc[cn][ct] = cc;
        }

        // row work: q read, Y1, y2 matvec, partial update (pre-ccr)
        float q[MT];
        {
            const float4* qp4 = reinterpret_cast<const float4*>(&s_q[gR][0]);
            float4 qx = qp4[0], qy = qp4[1];
            float2 qz = reinterpret_cast<const float2*>(qp4)[4];
            q[0] = qx.x; q[1] = qx.y; q[2] = qx.z; q[3] = qx.w;
            q[4] = qy.x; q[5] = qy.y; q[6] = qy.z; q[7] = qy.w;
            q[8] = qz.x; q[9] = qz.y;
        }
        float y1[MT];
        #pragma unroll
        for (int t = 0; t < MT; t++) y1[t] = cmpl ? q[t] : 0.f;
        unsigned mm = lmask;
        while (mm) {
            int b = __ffs(mm) - 1;
            mm &= mm - 1;
            const float4* rb4 = reinterpret_cast<const float4*>(&s_T[gR][b][0]);
            float4 ra = rb4[0], rb = rb4[1];
            float2 rc = reinterpret_cast<const float2*>(rb4)[4];
            y1[0] += sgn * ra.x; y1[1] += sgn * ra.y; y1[2] += sgn * ra.z; y1[3] += sgn * ra.w;
            y1[4] += sgn * rb.x; y1[5] += sgn * rb.y; y1[6] += sgn * rb.z; y1[7] += sgn * rb.w;
            y1[8] += sgn * rc.x; y1[9] += sgn * rc.y;
        }
        #pragma unroll
        for (int s = 0; s < MT; s++) {
            float y2 = 0.f;
            #pragma unroll
            for (int t = 0; t < MT; t++) y2 = fmaf(y1[t], c2p[s * MT + t], y2);
            lt[s] += tgl * y2 - Mc[s];           // ccr applied after barrier
        }
        __syncthreads();                         // (3) cc visible

        {
            const float4* cp = reinterpret_cast<const float4*>(&s_cc[gR][0]);
            float4 ca = cp[0], cb = cp[1];
            float2 c2 = reinterpret_cast<const float2*>(cp)[4];
            lt[0] -= ca.x; lt[1] -= ca.y; lt[2] -= ca.z; lt[3] -= ca.w;
            lt[4] -= cb.x; lt[5] -= cb.y; lt[6] -= cb.z; lt[7] -= cb.w;
            lt[8] -= c2.x; lt[9] -= c2.y;
        }
    }

    if (cvalid) {
        int nOut = nb + cn;
        if (nOut < NN)
            out[(size_t)nOut * (NTPL * MT) + kb * MT + ct] = qa;
    }
}

extern "C" void kernel_launch(void* const* d_in, const int* in_sizes, int n_in,
                              void* d_out, int out_size, void* d_ws, size_t ws_size,
                              hipStream_t stream) {
    const float* x      = (const float*)d_in[0];
    const int*   eidx   = (const int*)d_in[1];
    const float* tmpl   = (const float*)d_in[2];
    const float* tmplf  = (const float*)d_in[3];
    const float* alpha0 = (const float*)d_in[4];
    float*       outp   = (float*)d_out;

    const int* dst = eidx + NN * DEG;
    float* G = (float*)d_ws;
    const size_t gbytes = (size_t)NN * NTPL * MT * sizeof(float);       // 3,840,000
    const size_t mbytes = (size_t)NN * MM * sizeof(unsigned);           // 408,000
    int useG = (ws_size >= gbytes) ? 1 : 0;
    int useM = (ws_size >= gbytes + mbytes) ? 1 : 0;
    unsigned* maskg = (unsigned*)((char*)d_ws + gbytes);

    if (useG && useM) {
        pre_kernel<<<dim3(GBLK + MBLK), dim3(128), 0, stream>>>(
            x, tmplf, alpha0, dst, G, maskg);
    } else if (useG) {
        pre_kernel<<<dim3(GBLK), dim3(128), 0, stream>>>(
            x, tmplf, alpha0, dst, G, maskg);
    }

    srfgw_kernel<<<dim3(NN / NPB, NTPL / KPB), dim3(BS), 0, stream>>>(
        x, dst, tmpl, tmplf, alpha0, G, maskg, useG, useM, outp);
}